// Round 7
// baseline (162.389 us; speedup 1.0000x reference)
//
#include <hip/hip_runtime.h>
#include <hip/hip_bf16.h>
#include <math.h>

// N-BEATS SeasonalityBlock, fused persistent kernel, round 7.
// R6 structure minus setprio (2-wave/SIMD starvation suspect), depth-4 W
// prefetch (dist 3), waves_per_eu(2,2) for 256-VGPR headroom, split x-phase
// (right half hidden under layer-1 ks0..7), hoisted bias/basis preloads.
// 256 blocks x 512 threads (8 waves, 1 block/CU); block owns 64 batch rows.

#define BATCH 16384
#define ROWS  64

typedef __bf16 bf16x8 __attribute__((ext_vector_type(8)));
typedef float  f32x4  __attribute__((ext_vector_type(4)));

__device__ __forceinline__ unsigned short f2bf(float f) {
  union { float f; unsigned u; } v; v.f = f;
  unsigned r = v.u + 0x7fff + ((v.u >> 16) & 1);   // RTNE
  return (unsigned short)(r >> 16);
}

// ---------------- prep (unchanged from R6) --------------------------------
// Packed B layout in 16B units: unit u = (cf*KS + ks)*64 + lane holds
// W[cf*16 + (lane&15)][ks*32 + (lane>>4)*8 + e], e=0..7  (KS = K/32).
__global__ __launch_bounds__(256) void prep_kernel(
    const float* __restrict__ W1, const float* __restrict__ W2,
    const float* __restrict__ W3, const float* __restrict__ W4,
    const float* __restrict__ Wt,
    unsigned short* __restrict__ W1p, unsigned short* __restrict__ W2p,
    unsigned short* __restrict__ W3p, unsigned short* __restrict__ W4p,
    unsigned short* __restrict__ Wtp,
    unsigned short* __restrict__ basp) {
  const int t = blockIdx.x * 256 + threadIdx.x;
  if (t < 139264) {
    const float* src; unsigned short* dst; int u;
    if (t < 131072) {
      const int w = t >> 15; u = t & 32767;
      src = (w == 0) ? W1 : (w == 1) ? W2 : (w == 2) ? W3 : W4;
      dst = (w == 0) ? W1p : (w == 1) ? W2p : (w == 2) ? W3p : W4p;
    } else {
      u = t - 131072; src = Wt; dst = Wtp;
    }
    const int lane = u & 63, ks = (u >> 6) & 15, cf = u >> 10;
    const int col = cf * 16 + (lane & 15);
    const int k0  = ks * 32 + (lane >> 4) * 8;
    const float4* s = (const float4*)(src + (size_t)col * 512 + k0);
    const float4 a = s[0], b = s[1];
    uint4 o;
    o.x = f2bf(a.x) | ((unsigned)f2bf(a.y) << 16);
    o.y = f2bf(a.z) | ((unsigned)f2bf(a.w) << 16);
    o.z = f2bf(b.x) | ((unsigned)f2bf(b.y) << 16);
    o.w = f2bf(b.z) | ((unsigned)f2bf(b.w) << 16);
    ((uint4*)dst)[u] = o;
  } else if (t < 149504) {
    const int u = t - 139264;
    const int lane = u & 63, ks = (u >> 6) & 3, cf = u >> 8;
    const int col = cf * 16 + (lane & 15);
    const int r0  = ks * 32 + (lane >> 4) * 8;
    int l, L;
    if (col < 512) { l = col; L = 512; } else { l = col - 512; L = 128; }
    const float w0 = 6.283185307179586f * (float)l / (float)L;
    unsigned short e[8];
#pragma unroll
    for (int i = 0; i < 8; ++i) {
      const int r = r0 + i;
      const float ang = (float)(r >> 1) * w0;
      e[i] = f2bf((r & 1) ? sinf(ang) : cosf(ang));
    }
    uint4 o;
    o.x = e[0] | ((unsigned)e[1] << 16);
    o.y = e[2] | ((unsigned)e[3] << 16);
    o.z = e[4] | ((unsigned)e[5] << 16);
    o.w = e[6] | ((unsigned)e[7] << 16);
    ((uint4*)basp)[u] = o;
  }
}

__device__ __forceinline__ void wait_lds_and_barrier() {
  asm volatile("s_waitcnt lgkmcnt(0)" ::: "memory");
  __builtin_amdgcn_sched_barrier(0);
  __builtin_amdgcn_s_barrier();
  __builtin_amdgcn_sched_barrier(0);
}

// ---------------- layer k-steps [KB,KE) : acc += W-chunk @ h-chunk --------
// depth-4 rotating prefetch, issue distance 3 (slots: 16%4==0 so slot = ks&3
// uniformly across layers; cross-layer prefetch at ks=13..15 -> slots 0..2).
template <int KB, int KE, bool PF>
__device__ __forceinline__ void layer_ksteps(
    const unsigned short* hin, const bf16x8* __restrict__ wcur,
    const bf16x8* __restrict__ wnext,
    bf16x8 (&bv)[4][4], f32x4 (&acc)[4][4],
    const int (&rb)[4], const int (&am)[4], const int g) {
#pragma unroll
  for (int ks = KB; ks < KE; ++ks) {
    if (ks < 13) {
#pragma unroll
      for (int n = 0; n < 4; ++n)
        bv[(ks + 3) & 3][n] = wcur[n * 1024 + (ks + 3) * 64];
    } else if (PF) {
#pragma unroll
      for (int n = 0; n < 4; ++n)
        bv[(ks + 3) & 3][n] = wnext[n * 1024 + (ks - 13) * 64];
    }
    bf16x8 av[4];
    const int kb = ks * 64 + g * 16;
#pragma unroll
    for (int m = 0; m < 4; ++m)
      av[m] = *(const bf16x8*)((const char*)hin + rb[m] + (kb ^ am[m]));
#pragma unroll
    for (int m = 0; m < 4; ++m)
#pragma unroll
      for (int n = 0; n < 4; ++n)
        acc[m][n] = __builtin_amdgcn_mfma_f32_16x16x32_bf16(
            bv[ks & 3][n], av[m], acc[m][n], 0, 0, 0);
  }
}

// bias+relu epilogue -> hout (b64 writes), then barrier
__device__ __forceinline__ void layer_epilogue(
    unsigned short* hout, const float4 (&bias4)[4], f32x4 (&acc)[4][4],
    const int wv, const int lane) {
  const int l15 = lane & 15, g = lane >> 4;
#pragma unroll
  for (int m = 0; m < 4; ++m) {
    const int row = m * 16 + l15;
    const int sw  = (row & 7) << 4;
#pragma unroll
    for (int n = 0; n < 4; ++n) {
      const float v0 = fmaxf(acc[m][n][0] + bias4[n].x, 0.f);
      const float v1 = fmaxf(acc[m][n][1] + bias4[n].y, 0.f);
      const float v2 = fmaxf(acc[m][n][2] + bias4[n].z, 0.f);
      const float v3 = fmaxf(acc[m][n][3] + bias4[n].w, 0.f);
      uint2 o;
      o.x = f2bf(v0) | ((unsigned)f2bf(v1) << 16);
      o.y = f2bf(v2) | ((unsigned)f2bf(v3) << 16);
      const int c0 = (wv * 64 + n * 16 + g * 4) * 2;
      *(uint2*)((char*)hout + row * 1024 + (c0 ^ sw)) = o;
    }
  }
  wait_lds_and_barrier();
}

__device__ __forceinline__ void zero_acc(f32x4 (&acc)[4][4]) {
#pragma unroll
  for (int m = 0; m < 4; ++m)
#pragma unroll
    for (int n = 0; n < 4; ++n) acc[m][n] = (f32x4){0.f, 0.f, 0.f, 0.f};
}

// ---------------- fused mega-kernel --------------------------------------
__global__ __launch_bounds__(512)
__attribute__((amdgpu_waves_per_eu(2, 2)))
void fused_nbeats(
    const float* __restrict__ x,
    const bf16x8* __restrict__ W1p, const float* __restrict__ b1,
    const bf16x8* __restrict__ W2p, const float* __restrict__ b2,
    const bf16x8* __restrict__ W3p, const float* __restrict__ b3,
    const bf16x8* __restrict__ W4p, const float* __restrict__ b4,
    const bf16x8* __restrict__ Wtp,
    const bf16x8* __restrict__ basp,
    float* __restrict__ out) {
  __shared__ __align__(16) unsigned short h0[ROWS * 512];   // 64 KB
  __shared__ __align__(16) unsigned short h1[ROWS * 512];   // 64 KB

  const int tid  = threadIdx.x;
  const int lane = tid & 63;
  const int wv   = tid >> 6;
  const int l15  = lane & 15, g = lane >> 4;
  const int r0   = blockIdx.x * ROWS;

  const bf16x8* w1 = W1p + (size_t)wv * 4096 + lane;
  const bf16x8* w2 = W2p + (size_t)wv * 4096 + lane;
  const bf16x8* w3 = W3p + (size_t)wv * 4096 + lane;
  const bf16x8* w4 = W4p + (size_t)wv * 4096 + lane;

  int rb[4], am[4];
#pragma unroll
  for (int m = 0; m < 4; ++m) {
    const int row = m * 16 + l15;
    rb[m] = row * 1024;
    am[m] = (row & 7) << 4;
  }

  bf16x8 bv[4][4];
  // initial fill: W1 k-steps 0..2 -> slots 0..2 (issued before x loads)
#pragma unroll
  for (int s = 0; s < 3; ++s)
#pragma unroll
    for (int n = 0; n < 4; ++n) bv[s][n] = w1[n * 1024 + s * 64];

  const float4* xs = (const float4*)(x + (size_t)r0 * 512);

  // ---- phase 0a: x cols [0,256) fp32 -> h0 left half ----
#pragma unroll
  for (int j = 0; j < 8; ++j) {
    const int idx = tid + j * 512;        // [64 rows][64 float4] left half
    const int row = idx >> 6, c4 = idx & 63;
    const float4 v = xs[row * 128 + c4];
    uint2 o;
    o.x = f2bf(v.x) | ((unsigned)f2bf(v.y) << 16);
    o.y = f2bf(v.z) | ((unsigned)f2bf(v.w) << 16);
    *(uint2*)((char*)h0 + row * 1024 + ((c4 * 8) ^ ((row & 7) << 4))) = o;
  }
  wait_lds_and_barrier();

  // ---- layer 1 with x right half hidden under ks0..7 ----
  f32x4 acc[4][4];
  zero_acc(acc);
  {
    float4 xr[8];
#pragma unroll
    for (int j = 0; j < 8; ++j) {
      const int idx = tid + j * 512;
      const int row = idx >> 6, c4 = idx & 63;
      xr[j] = xs[row * 128 + 64 + c4];
    }
    layer_ksteps<0, 8, false>(h0, w1, w1, bv, acc, rb, am, g);
#pragma unroll
    for (int j = 0; j < 8; ++j) {
      const int idx = tid + j * 512;
      const int row = idx >> 6, c4b = 64 + (idx & 63);
      uint2 o;
      o.x = f2bf(xr[j].x) | ((unsigned)f2bf(xr[j].y) << 16);
      o.y = f2bf(xr[j].z) | ((unsigned)f2bf(xr[j].w) << 16);
      *(uint2*)((char*)h0 + row * 1024 + ((c4b * 8) ^ ((row & 7) << 4))) = o;
    }
    wait_lds_and_barrier();
  }
  {
    float4 bias4[4];
#pragma unroll
    for (int n = 0; n < 4; ++n)
      bias4[n] = *(const float4*)(b1 + wv * 64 + n * 16 + g * 4);
    layer_ksteps<8, 16, true>(h0, w1, w2, bv, acc, rb, am, g);
    layer_epilogue(h1, bias4, acc, wv, lane);
  }

  // ---- layers 2..4 ----
  {
    float4 bias4[4];
#pragma unroll
    for (int n = 0; n < 4; ++n)
      bias4[n] = *(const float4*)(b2 + wv * 64 + n * 16 + g * 4);
    zero_acc(acc);
    layer_ksteps<0, 16, true>(h1, w2, w3, bv, acc, rb, am, g);
    layer_epilogue(h0, bias4, acc, wv, lane);
  }
  {
    float4 bias4[4];
#pragma unroll
    for (int n = 0; n < 4; ++n)
      bias4[n] = *(const float4*)(b3 + wv * 64 + n * 16 + g * 4);
    zero_acc(acc);
    layer_ksteps<0, 16, true>(h0, w3, w4, bv, acc, rb, am, g);
    layer_epilogue(h1, bias4, acc, wv, lane);
  }
  {
    float4 bias4[4];
#pragma unroll
    for (int n = 0; n < 4; ++n)
      bias4[n] = *(const float4*)(b4 + wv * 64 + n * 16 + g * 4);
    zero_acc(acc);
    layer_ksteps<0, 16, false>(h1, w4, w4, bv, acc, rb, am, g);
    layer_epilogue(h0, bias4, acc, wv, lane);
  }

  // ---- theta = h4 @ Wt^T (h4 in h0); preload basis B-frags meanwhile ----
  const bf16x8* bb = basp + (size_t)wv * 1280 + lane;   // cf = wv*5+n, KS=4
  bf16x8 bvv[5][4];
  {
#pragma unroll
    for (int n = 0; n < 5; ++n)
#pragma unroll
      for (int ks = 0; ks < 4; ++ks) bvv[n][ks] = bb[n * 256 + ks * 64];

    const bf16x8* tb = Wtp + (size_t)wv * 1024 + lane;
    bf16x8 tv[4];
#pragma unroll
    for (int s = 0; s < 3; ++s) tv[s] = tb[s * 64];

    f32x4 tacc[4];
#pragma unroll
    for (int m = 0; m < 4; ++m) tacc[m] = (f32x4){0.f, 0.f, 0.f, 0.f};
#pragma unroll
    for (int ks = 0; ks < 16; ++ks) {
      if (ks < 13) tv[(ks + 3) & 3] = tb[(ks + 3) * 64];
      bf16x8 av[4];
      const int kb = ks * 64 + g * 16;
#pragma unroll
      for (int m = 0; m < 4; ++m)
        av[m] = *(const bf16x8*)((const char*)h0 + rb[m] + (kb ^ am[m]));
#pragma unroll
      for (int m = 0; m < 4; ++m)
        tacc[m] = __builtin_amdgcn_mfma_f32_16x16x32_bf16(
            tv[ks & 3], av[m], tacc[m], 0, 0, 0);
    }
    // theta -> h1 as [64][128] bf16 (256B rows, same swizzle)
#pragma unroll
    for (int m = 0; m < 4; ++m) {
      const int row = m * 16 + l15;
      const int sw  = (row & 7) << 4;
      uint2 o;
      o.x = f2bf(tacc[m][0]) | ((unsigned)f2bf(tacc[m][1]) << 16);
      o.y = f2bf(tacc[m][2]) | ((unsigned)f2bf(tacc[m][3]) << 16);
      const int c0 = (wv * 16 + g * 4) * 2;
      *(uint2*)((char*)h1 + row * 256 + (c0 ^ sw)) = o;
    }
  }
  wait_lds_and_barrier();

  // ---- backcast/forecast: out = theta @ basT^T (wave wv -> 80 cols) ----
  {
    f32x4 facc[4][5];
#pragma unroll
    for (int m = 0; m < 4; ++m)
#pragma unroll
      for (int n = 0; n < 5; ++n) facc[m][n] = (f32x4){0.f, 0.f, 0.f, 0.f};
    int rb2[4];
#pragma unroll
    for (int m = 0; m < 4; ++m) rb2[m] = (m * 16 + l15) * 256;
#pragma unroll
    for (int ks = 0; ks < 4; ++ks) {
      bf16x8 av[4];
      const int kb = ks * 64 + g * 16;
#pragma unroll
      for (int m = 0; m < 4; ++m)
        av[m] = *(const bf16x8*)((const char*)h1 + rb2[m] + (kb ^ am[m]));
#pragma unroll
      for (int n = 0; n < 5; ++n)
#pragma unroll
        for (int m = 0; m < 4; ++m)
          facc[m][n] = __builtin_amdgcn_mfma_f32_16x16x32_bf16(
              bvv[n][ks], av[m], facc[m][n], 0, 0, 0);
    }
    // store: lane (g,l15), frag (m,n): row r0+m*16+l15,
    // cols wv*80+n*16+g*4+(0..3) -> one dwordx4
#pragma unroll
    for (int n = 0; n < 5; ++n) {
      const int c0 = wv * 80 + n * 16 + g * 4;
#pragma unroll
      for (int m = 0; m < 4; ++m) {
        const int row = r0 + m * 16 + l15;
        float4 o = make_float4(facc[m][n][0], facc[m][n][1],
                               facc[m][n][2], facc[m][n][3]);
        if (c0 < 512)
          *(float4*)(out + (size_t)row * 512 + c0) = o;
        else
          *(float4*)(out + (size_t)BATCH * 512 + (size_t)row * 128 + (c0 - 512)) = o;
      }
    }
  }
}

// ---------------- launch --------------------------------------------------
extern "C" void kernel_launch(void* const* d_in, const int* in_sizes, int n_in,
                              void* d_out, int out_size, void* d_ws, size_t ws_size,
                              hipStream_t stream) {
  const float* x  = (const float*)d_in[0];
  const float* W1 = (const float*)d_in[1];
  const float* b1 = (const float*)d_in[2];
  const float* W2 = (const float*)d_in[3];
  const float* b2 = (const float*)d_in[4];
  const float* W3 = (const float*)d_in[5];
  const float* b3 = (const float*)d_in[6];
  const float* W4 = (const float*)d_in[7];
  const float* b4 = (const float*)d_in[8];
  const float* Wt = (const float*)d_in[9];

  unsigned short* ws  = (unsigned short*)d_ws;
  unsigned short* W1p = ws;                       // 262144 elems each
  unsigned short* W2p = ws + 262144;
  unsigned short* W3p = ws + 524288;
  unsigned short* W4p = ws + 786432;
  unsigned short* Wtp = ws + 1048576;             // 65536
  unsigned short* basp = ws + 1114112;            // 640*128 = 81920

  prep_kernel<<<584, 256, 0, stream>>>(W1, W2, W3, W4, Wt,
                                       W1p, W2p, W3p, W4p, Wtp, basp);
  fused_nbeats<<<BATCH / ROWS, 512, 0, stream>>>(
      x, (const bf16x8*)W1p, b1, (const bf16x8*)W2p, b2,
      (const bf16x8*)W3p, b3, (const bf16x8*)W4p, b4,
      (const bf16x8*)Wtp, (const bf16x8*)basp, (float*)d_out);
}

// Round 8
// 161.459 us; speedup vs baseline: 1.0058x; 1.0058x over previous
//
#include <hip/hip_runtime.h>
#include <hip/hip_bf16.h>
#include <math.h>

// N-BEATS SeasonalityBlock, fused persistent kernel, round 8.
// Base = R6 (proven 54.4us fused). Deltas, each latency-targeted:
//  - no setprio anywhere (2-wave/SIMD starvation, m190)
//  - W prefetch depth-4 / issue-distance-3 (was 3/2)
//  - per-wave k-offset stagger (wave wv starts K at kstep 2*wv) to
//    decorrelate vmcnt stalls of the 2 waves sharing a SIMD
// 256 blocks x 512 threads (8 waves, 1 block/CU); block owns 64 batch rows.

#define BATCH 16384
#define ROWS  64

typedef __bf16 bf16x8 __attribute__((ext_vector_type(8)));
typedef float  f32x4  __attribute__((ext_vector_type(4)));

__device__ __forceinline__ unsigned short f2bf(float f) {
  union { float f; unsigned u; } v; v.f = f;
  unsigned r = v.u + 0x7fff + ((v.u >> 16) & 1);   // RTNE
  return (unsigned short)(r >> 16);
}

// ---------------- prep (unchanged) ----------------------------------------
// Packed B layout in 16B units: unit u = (cf*KS + ks)*64 + lane holds
// W[cf*16 + (lane&15)][ks*32 + (lane>>4)*8 + e], e=0..7  (KS = K/32).
__global__ __launch_bounds__(256) void prep_kernel(
    const float* __restrict__ W1, const float* __restrict__ W2,
    const float* __restrict__ W3, const float* __restrict__ W4,
    const float* __restrict__ Wt,
    unsigned short* __restrict__ W1p, unsigned short* __restrict__ W2p,
    unsigned short* __restrict__ W3p, unsigned short* __restrict__ W4p,
    unsigned short* __restrict__ Wtp,
    unsigned short* __restrict__ basp) {
  const int t = blockIdx.x * 256 + threadIdx.x;
  if (t < 139264) {
    const float* src; unsigned short* dst; int u;
    if (t < 131072) {
      const int w = t >> 15; u = t & 32767;
      src = (w == 0) ? W1 : (w == 1) ? W2 : (w == 2) ? W3 : W4;
      dst = (w == 0) ? W1p : (w == 1) ? W2p : (w == 2) ? W3p : W4p;
    } else {
      u = t - 131072; src = Wt; dst = Wtp;
    }
    const int lane = u & 63, ks = (u >> 6) & 15, cf = u >> 10;
    const int col = cf * 16 + (lane & 15);
    const int k0  = ks * 32 + (lane >> 4) * 8;
    const float4* s = (const float4*)(src + (size_t)col * 512 + k0);
    const float4 a = s[0], b = s[1];
    uint4 o;
    o.x = f2bf(a.x) | ((unsigned)f2bf(a.y) << 16);
    o.y = f2bf(a.z) | ((unsigned)f2bf(a.w) << 16);
    o.z = f2bf(b.x) | ((unsigned)f2bf(b.y) << 16);
    o.w = f2bf(b.z) | ((unsigned)f2bf(b.w) << 16);
    ((uint4*)dst)[u] = o;
  } else if (t < 149504) {
    const int u = t - 139264;
    const int lane = u & 63, ks = (u >> 6) & 3, cf = u >> 8;
    const int col = cf * 16 + (lane & 15);
    const int r0  = ks * 32 + (lane >> 4) * 8;
    int l, L;
    if (col < 512) { l = col; L = 512; } else { l = col - 512; L = 128; }
    const float w0 = 6.283185307179586f * (float)l / (float)L;
    unsigned short e[8];
#pragma unroll
    for (int i = 0; i < 8; ++i) {
      const int r = r0 + i;
      const float ang = (float)(r >> 1) * w0;
      e[i] = f2bf((r & 1) ? sinf(ang) : cosf(ang));
    }
    uint4 o;
    o.x = e[0] | ((unsigned)e[1] << 16);
    o.y = e[2] | ((unsigned)e[3] << 16);
    o.z = e[4] | ((unsigned)e[5] << 16);
    o.w = e[6] | ((unsigned)e[7] << 16);
    ((uint4*)basp)[u] = o;
  }
}

__device__ __forceinline__ void wait_lds_and_barrier() {
  asm volatile("s_waitcnt lgkmcnt(0)" ::: "memory");
  __builtin_amdgcn_sched_barrier(0);
  __builtin_amdgcn_s_barrier();
  __builtin_amdgcn_sched_barrier(0);
}

// ---------------- one FC layer k-loop, staggered --------------------------
// Wave consumes k-steps in order (p+off)&15, p=0..15. Depth-4 rotating
// prefetch, issue distance 3; slot = p&3 (16%4==0 -> uniform across layers).
// At p=13..15 prefetch NEXT layer's first 3 staggered k-steps into slots 0..2.
template <bool PF>
__device__ __forceinline__ void layer_ksteps(
    const unsigned short* hin, const bf16x8* __restrict__ wcur,
    const bf16x8* __restrict__ wnext,
    bf16x8 (&bv)[4][4], f32x4 (&acc)[4][4],
    const int (&rb)[4], const int (&am)[4], const int g, const int off) {
#pragma unroll
  for (int p = 0; p < 16; ++p) {
    if (p < 13) {
      const int ksl = (p + 3 + off) & 15;
#pragma unroll
      for (int n = 0; n < 4; ++n)
        bv[(p + 3) & 3][n] = wcur[n * 1024 + ksl * 64];
    } else if (PF) {
      const int ksl = (p - 13 + off) & 15;
#pragma unroll
      for (int n = 0; n < 4; ++n)
        bv[(p + 3) & 3][n] = wnext[n * 1024 + ksl * 64];
    }
    const int ks = (p + off) & 15;
    bf16x8 av[4];
    const int kb = ks * 64 + g * 16;
#pragma unroll
    for (int m = 0; m < 4; ++m)
      av[m] = *(const bf16x8*)((const char*)hin + rb[m] + (kb ^ am[m]));
#pragma unroll
    for (int m = 0; m < 4; ++m)
#pragma unroll
      for (int n = 0; n < 4; ++n)
        acc[m][n] = __builtin_amdgcn_mfma_f32_16x16x32_bf16(
            bv[p & 3][n], av[m], acc[m][n], 0, 0, 0);
  }
}

// bias+relu epilogue -> hout (b64 writes), then barrier
__device__ __forceinline__ void layer_epilogue(
    unsigned short* hout, const float* __restrict__ bias, f32x4 (&acc)[4][4],
    const int wv, const int lane) {
  const int l15 = lane & 15, g = lane >> 4;
  float4 bias4[4];
#pragma unroll
  for (int n = 0; n < 4; ++n)
    bias4[n] = *(const float4*)(bias + wv * 64 + n * 16 + g * 4);
#pragma unroll
  for (int m = 0; m < 4; ++m) {
    const int row = m * 16 + l15;
    const int sw  = (row & 7) << 4;
#pragma unroll
    for (int n = 0; n < 4; ++n) {
      const float v0 = fmaxf(acc[m][n][0] + bias4[n].x, 0.f);
      const float v1 = fmaxf(acc[m][n][1] + bias4[n].y, 0.f);
      const float v2 = fmaxf(acc[m][n][2] + bias4[n].z, 0.f);
      const float v3 = fmaxf(acc[m][n][3] + bias4[n].w, 0.f);
      uint2 o;
      o.x = f2bf(v0) | ((unsigned)f2bf(v1) << 16);
      o.y = f2bf(v2) | ((unsigned)f2bf(v3) << 16);
      const int c0 = (wv * 64 + n * 16 + g * 4) * 2;
      *(uint2*)((char*)hout + row * 1024 + (c0 ^ sw)) = o;
    }
  }
  wait_lds_and_barrier();
}

__device__ __forceinline__ void zero_acc(f32x4 (&acc)[4][4]) {
#pragma unroll
  for (int m = 0; m < 4; ++m)
#pragma unroll
    for (int n = 0; n < 4; ++n) acc[m][n] = (f32x4){0.f, 0.f, 0.f, 0.f};
}

// ---------------- fused mega-kernel --------------------------------------
__global__ __launch_bounds__(512, 2) void fused_nbeats(
    const float* __restrict__ x,
    const bf16x8* __restrict__ W1p, const float* __restrict__ b1,
    const bf16x8* __restrict__ W2p, const float* __restrict__ b2,
    const bf16x8* __restrict__ W3p, const float* __restrict__ b3,
    const bf16x8* __restrict__ W4p, const float* __restrict__ b4,
    const bf16x8* __restrict__ Wtp,
    const bf16x8* __restrict__ basp,
    float* __restrict__ out) {
  __shared__ __align__(16) unsigned short h0[ROWS * 512];   // 64 KB
  __shared__ __align__(16) unsigned short h1[ROWS * 512];   // 64 KB

  const int tid  = threadIdx.x;
  const int lane = tid & 63;
  const int wv   = tid >> 6;
  const int l15  = lane & 15, g = lane >> 4;
  const int r0   = blockIdx.x * ROWS;
  const int off  = (wv * 2) & 15;        // per-wave k-step stagger

  const bf16x8* w1 = W1p + (size_t)wv * 4096 + lane;
  const bf16x8* w2 = W2p + (size_t)wv * 4096 + lane;
  const bf16x8* w3 = W3p + (size_t)wv * 4096 + lane;
  const bf16x8* w4 = W4p + (size_t)wv * 4096 + lane;

  int rb[4], am[4];
#pragma unroll
  for (int m = 0; m < 4; ++m) {
    const int row = m * 16 + l15;
    rb[m] = row * 1024;
    am[m] = (row & 7) << 4;
  }

  bf16x8 bv[4][4];
  // initial fill: W1 staggered k-steps off..off+2 -> slots 0..2
#pragma unroll
  for (int s = 0; s < 3; ++s) {
    const int ksl = (s + off) & 15;
#pragma unroll
    for (int n = 0; n < 4; ++n) bv[s][n] = w1[n * 1024 + ksl * 64];
  }

  // ---- phase 0: x fp32 -> h0 bf16 (swizzled rows, 1024B stride) ----
  {
    const float4* xs = (const float4*)(x + (size_t)r0 * 512);
#pragma unroll
    for (int j = 0; j < 16; ++j) {
      const int f = tid + j * 512;          // float4 index in [64][128]
      const int row = f >> 7, c4 = f & 127;
      const float4 v = xs[f];
      uint2 o;
      o.x = f2bf(v.x) | ((unsigned)f2bf(v.y) << 16);
      o.y = f2bf(v.z) | ((unsigned)f2bf(v.w) << 16);
      *(uint2*)((char*)h0 + row * 1024 + ((c4 * 8) ^ ((row & 7) << 4))) = o;
    }
  }
  wait_lds_and_barrier();

  // ---- 4 FC+ReLU layers (ping-pong, one barrier each) ----
  f32x4 acc[4][4];
  zero_acc(acc);
  layer_ksteps<true >(h0, w1, w2, bv, acc, rb, am, g, off);
  layer_epilogue(h1, b1, acc, wv, lane);
  zero_acc(acc);
  layer_ksteps<true >(h1, w2, w3, bv, acc, rb, am, g, off);
  layer_epilogue(h0, b2, acc, wv, lane);
  zero_acc(acc);
  layer_ksteps<true >(h0, w3, w4, bv, acc, rb, am, g, off);
  layer_epilogue(h1, b3, acc, wv, lane);
  zero_acc(acc);
  layer_ksteps<false>(h1, w4, w4, bv, acc, rb, am, g, off);
  layer_epilogue(h0, b4, acc, wv, lane);

  // ---- theta = h4 @ Wt^T (h4 in h0); wave wv -> theta cols wv*16..+15 ----
  {
    const bf16x8* tb = Wtp + (size_t)wv * 1024 + lane;
    bf16x8 tv[4];                          // depth-4 / dist-3 rolling
#pragma unroll
    for (int s = 0; s < 3; ++s) tv[s] = tb[((s + off) & 15) * 64];

    f32x4 tacc[4];
#pragma unroll
    for (int m = 0; m < 4; ++m) tacc[m] = (f32x4){0.f, 0.f, 0.f, 0.f};
#pragma unroll
    for (int p = 0; p < 16; ++p) {
      if (p < 13) tv[(p + 3) & 3] = tb[((p + 3 + off) & 15) * 64];
      const int ks = (p + off) & 15;
      bf16x8 av[4];
      const int kb = ks * 64 + g * 16;
#pragma unroll
      for (int m = 0; m < 4; ++m)
        av[m] = *(const bf16x8*)((const char*)h0 + rb[m] + (kb ^ am[m]));
#pragma unroll
      for (int m = 0; m < 4; ++m)
        tacc[m] = __builtin_amdgcn_mfma_f32_16x16x32_bf16(
            tv[p & 3], av[m], tacc[m], 0, 0, 0);
    }
    // theta -> h1 as [64][128] bf16 (256B rows, same swizzle)
#pragma unroll
    for (int m = 0; m < 4; ++m) {
      const int row = m * 16 + l15;
      const int sw  = (row & 7) << 4;
      uint2 o;
      o.x = f2bf(tacc[m][0]) | ((unsigned)f2bf(tacc[m][1]) << 16);
      o.y = f2bf(tacc[m][2]) | ((unsigned)f2bf(tacc[m][3]) << 16);
      const int c0 = (wv * 16 + g * 4) * 2;
      *(uint2*)((char*)h1 + row * 256 + (c0 ^ sw)) = o;
    }
  }
  wait_lds_and_barrier();

  // ---- backcast/forecast: out = theta @ basT^T (wave wv -> 80 cols) ----
  {
    const bf16x8* bb = basp + (size_t)wv * 1280 + lane;   // cf = wv*5+n, KS=4
    bf16x8 bvv[2][5];                      // rolling depth-2
#pragma unroll
    for (int n = 0; n < 5; ++n) bvv[0][n] = bb[n * 256];

    f32x4 facc[4][5];
#pragma unroll
    for (int m = 0; m < 4; ++m)
#pragma unroll
      for (int n = 0; n < 5; ++n) facc[m][n] = (f32x4){0.f, 0.f, 0.f, 0.f};
    int rb2[4];
#pragma unroll
    for (int m = 0; m < 4; ++m) rb2[m] = (m * 16 + l15) * 256;
#pragma unroll
    for (int ks = 0; ks < 4; ++ks) {
      if (ks < 3) {
#pragma unroll
        for (int n = 0; n < 5; ++n) bvv[(ks + 1) & 1][n] = bb[n * 256 + (ks + 1) * 64];
      }
      bf16x8 av[4];
      const int kb = ks * 64 + g * 16;
#pragma unroll
      for (int m = 0; m < 4; ++m)
        av[m] = *(const bf16x8*)((const char*)h1 + rb2[m] + (kb ^ am[m]));
#pragma unroll
      for (int n = 0; n < 5; ++n)
#pragma unroll
        for (int m = 0; m < 4; ++m)
          facc[m][n] = __builtin_amdgcn_mfma_f32_16x16x32_bf16(
              bvv[ks & 1][n], av[m], facc[m][n], 0, 0, 0);
    }
    // store: lane (g,l15), frag (m,n): row r0+m*16+l15,
    // cols wv*80+n*16+g*4+(0..3) -> one dwordx4
#pragma unroll
    for (int n = 0; n < 5; ++n) {
      const int c0 = wv * 80 + n * 16 + g * 4;
#pragma unroll
      for (int m = 0; m < 4; ++m) {
        const int row = r0 + m * 16 + l15;
        float4 o = make_float4(facc[m][n][0], facc[m][n][1],
                               facc[m][n][2], facc[m][n][3]);
        if (c0 < 512)
          *(float4*)(out + (size_t)row * 512 + c0) = o;
        else
          *(float4*)(out + (size_t)BATCH * 512 + (size_t)row * 128 + (c0 - 512)) = o;
      }
    }
  }
}

// ---------------- launch --------------------------------------------------
extern "C" void kernel_launch(void* const* d_in, const int* in_sizes, int n_in,
                              void* d_out, int out_size, void* d_ws, size_t ws_size,
                              hipStream_t stream) {
  const float* x  = (const float*)d_in[0];
  const float* W1 = (const float*)d_in[1];
  const float* b1 = (const float*)d_in[2];
  const float* W2 = (const float*)d_in[3];
  const float* b2 = (const float*)d_in[4];
  const float* W3 = (const float*)d_in[5];
  const float* b3 = (const float*)d_in[6];
  const float* W4 = (const float*)d_in[7];
  const float* b4 = (const float*)d_in[8];
  const float* Wt = (const float*)d_in[9];

  unsigned short* ws  = (unsigned short*)d_ws;
  unsigned short* W1p = ws;                       // 262144 elems each
  unsigned short* W2p = ws + 262144;
  unsigned short* W3p = ws + 524288;
  unsigned short* W4p = ws + 786432;
  unsigned short* Wtp = ws + 1048576;             // 65536
  unsigned short* basp = ws + 1114112;            // 640*128 = 81920

  prep_kernel<<<584, 256, 0, stream>>>(W1, W2, W3, W4, Wt,
                                       W1p, W2p, W3p, W4p, Wtp, basp);
  fused_nbeats<<<BATCH / ROWS, 512, 0, stream>>>(
      x, (const bf16x8*)W1p, b1, (const bf16x8*)W2p, b2,
      (const bf16x8*)W3p, b3, (const bf16x8*)W4p, b4,
      (const bf16x8*)Wtp, (const bf16x8*)basp, (float*)d_out);
}

// Round 9
// 146.801 us; speedup vs baseline: 1.1062x; 1.0998x over previous
//
#include <hip/hip_runtime.h>
#include <hip/hip_bf16.h>
#include <math.h>

// N-BEATS SeasonalityBlock, fused persistent kernel, round 9.
// W staged via wave-private global_load_lds double-buffer + counted vmcnt(4)
// (T3/T4): DMA engine holds the outstanding-ness, zero W registers, no
// barriers inside the k-loop (W slices wave-private; h stable per layer).
// h single-buffer in-place (64KB) + Wc[2][32KB] = 128KB LDS. No setprio.
// 256 blocks x 512 threads (8 waves, 1 block/CU); block owns 64 batch rows.

#define BATCH 16384
#define ROWS  64

typedef __bf16 bf16x8 __attribute__((ext_vector_type(8)));
typedef float  f32x4  __attribute__((ext_vector_type(4)));

__device__ __forceinline__ unsigned short f2bf(float f) {
  union { float f; unsigned u; } v; v.f = f;
  unsigned r = v.u + 0x7fff + ((v.u >> 16) & 1);   // RTNE
  return (unsigned short)(r >> 16);
}

__device__ __forceinline__ void async_copy16(const void* g, void* l) {
  __builtin_amdgcn_global_load_lds(
      (const __attribute__((address_space(1))) unsigned int*)g,
      (__attribute__((address_space(3))) unsigned int*)l,
      16, 0, 0);
}

__device__ __forceinline__ void wait_vmcnt4() {
  asm volatile("s_waitcnt vmcnt(4)" ::: "memory");
}
__device__ __forceinline__ void wait_vmcnt0() {
  asm volatile("s_waitcnt vmcnt(0)" ::: "memory");
}
__device__ __forceinline__ void wait_lds_and_barrier() {
  asm volatile("s_waitcnt lgkmcnt(0)" ::: "memory");
  __builtin_amdgcn_sched_barrier(0);
  __builtin_amdgcn_s_barrier();
  __builtin_amdgcn_sched_barrier(0);
}

// ---------------- prep ----------------------------------------------------
// Layer weights W1..W4 packed DMA-ready, 16B units:
//   unit u (per matrix): c=u>>11, wv=(u>>8)&7, n=(u>>6)&3, lane=u&63
//   holds W[(wv*4+n)*16 + (lane&15)][c*32 + (lane>>4)*8 + e], e=0..7.
//   => chunk c = 32KB; wave wv's slice = 4KB contiguous at wv*4096.
// Wt packed for register stream: unit u: cf=u>>10, ks=(u>>6)&15, lane=u&63
//   holds Wt[cf*16+(lane&15)][ks*32+(lane>>4)*8+e].
// Basis: 640 cols x 128 k, KS=4, same per-frag layout (cf over 40).
__global__ __launch_bounds__(256) void prep_kernel(
    const float* __restrict__ W1, const float* __restrict__ W2,
    const float* __restrict__ W3, const float* __restrict__ W4,
    const float* __restrict__ Wt,
    unsigned short* __restrict__ W1p, unsigned short* __restrict__ W2p,
    unsigned short* __restrict__ W3p, unsigned short* __restrict__ W4p,
    unsigned short* __restrict__ Wtp,
    unsigned short* __restrict__ basp) {
  const int t = blockIdx.x * 256 + threadIdx.x;
  if (t < 131072) {
    const int w = t >> 15;
    const int u = t & 32767;
    const float* src = (w == 0) ? W1 : (w == 1) ? W2 : (w == 2) ? W3 : W4;
    unsigned short* dst = (w == 0) ? W1p : (w == 1) ? W2p : (w == 2) ? W3p : W4p;
    const int c = u >> 11, wv = (u >> 8) & 7, n = (u >> 6) & 3, lane = u & 63;
    const int col = (wv * 4 + n) * 16 + (lane & 15);
    const int k0  = c * 32 + (lane >> 4) * 8;
    const float4* s = (const float4*)(src + (size_t)col * 512 + k0);
    const float4 a = s[0], b = s[1];
    uint4 o;
    o.x = f2bf(a.x) | ((unsigned)f2bf(a.y) << 16);
    o.y = f2bf(a.z) | ((unsigned)f2bf(a.w) << 16);
    o.z = f2bf(b.x) | ((unsigned)f2bf(b.y) << 16);
    o.w = f2bf(b.z) | ((unsigned)f2bf(b.w) << 16);
    ((uint4*)dst)[u] = o;
  } else if (t < 139264) {
    const int u = t - 131072;
    const int lane = u & 63, ks = (u >> 6) & 15, cf = u >> 10;
    const int col = cf * 16 + (lane & 15);
    const int k0  = ks * 32 + (lane >> 4) * 8;
    const float4* s = (const float4*)(Wt + (size_t)col * 512 + k0);
    const float4 a = s[0], b = s[1];
    uint4 o;
    o.x = f2bf(a.x) | ((unsigned)f2bf(a.y) << 16);
    o.y = f2bf(a.z) | ((unsigned)f2bf(a.w) << 16);
    o.z = f2bf(b.x) | ((unsigned)f2bf(b.y) << 16);
    o.w = f2bf(b.z) | ((unsigned)f2bf(b.w) << 16);
    ((uint4*)Wtp)[u] = o;
  } else if (t < 149504) {
    const int u = t - 139264;
    const int lane = u & 63, ks = (u >> 6) & 3, cf = u >> 8;
    const int col = cf * 16 + (lane & 15);
    const int r0  = ks * 32 + (lane >> 4) * 8;
    int l, L;
    if (col < 512) { l = col; L = 512; } else { l = col - 512; L = 128; }
    const float w0 = 6.283185307179586f * (float)l / (float)L;
    unsigned short e[8];
#pragma unroll
    for (int i = 0; i < 8; ++i) {
      const int r = r0 + i;
      const float ang = (float)(r >> 1) * w0;
      e[i] = f2bf((r & 1) ? sinf(ang) : cosf(ang));
    }
    uint4 o;
    o.x = e[0] | ((unsigned)e[1] << 16);
    o.y = e[2] | ((unsigned)e[3] << 16);
    o.z = e[4] | ((unsigned)e[5] << 16);
    o.w = e[6] | ((unsigned)e[7] << 16);
    ((uint4*)basp)[u] = o;
  }
}

__device__ __forceinline__ void zero_acc(f32x4 (&acc)[4][4]) {
#pragma unroll
  for (int m = 0; m < 4; ++m)
#pragma unroll
    for (int n = 0; n < 4; ++n) acc[m][n] = (f32x4){0.f, 0.f, 0.f, 0.f};
}

// ---------------- one FC+ReLU layer, in-place on h ------------------------
// Per phase c (global chunk G = L*16+c):
//   wait vmcnt(4) [chunk G landed; G+1 still in flight]
//   ds_read 4 W-frags (own slice of Wc[c&1]) + 4 A-frags (h)
//   16 MFMA (swapped operands)
//   sched_barrier(0); issue DMA(G+2) into Wc[c&1]  [in-order exec => my
//     ds_reads of this buffer already completed; slice is wave-private]
template <int L>
__device__ __forceinline__ void layer512(
    unsigned short* h, unsigned short (*Wc)[16384], const char* Wall,
    const float* __restrict__ bias,
    const int wv, const int lane, const int (&rb)[4], const int (&am)[4]) {
  const int l15 = lane & 15, g = lane >> 4;
  f32x4 acc[4][4];
  zero_acc(acc);

  const int woff = wv * 4096 + lane * 16;   // byte offset of my lane in a chunk

#pragma unroll
  for (int c = 0; c < 16; ++c) {
    const int G = L * 16 + c;
    if (G == 63) wait_vmcnt0(); else wait_vmcnt4();

    bf16x8 wf[4];
#pragma unroll
    for (int n = 0; n < 4; ++n)
      wf[n] = *(const bf16x8*)((const char*)Wc[c & 1] + wv * 4096 + n * 1024 + lane * 16);
    bf16x8 av[4];
    const int kb = c * 64 + g * 16;
#pragma unroll
    for (int m = 0; m < 4; ++m)
      av[m] = *(const bf16x8*)((const char*)h + rb[m] + (kb ^ am[m]));
#pragma unroll
    for (int m = 0; m < 4; ++m)
#pragma unroll
      for (int n = 0; n < 4; ++n)
        acc[m][n] = __builtin_amdgcn_mfma_f32_16x16x32_bf16(
            wf[n], av[m], acc[m][n], 0, 0, 0);

    __builtin_amdgcn_sched_barrier(0);
    if (G + 2 <= 63) {
      const char* gsrc = Wall + (size_t)(G + 2) * 32768 + woff;
      char* ldst = (char*)Wc[c & 1] + woff;
#pragma unroll
      for (int j = 0; j < 4; ++j)
        async_copy16(gsrc + j * 1024, ldst + j * 1024);
    }
    __builtin_amdgcn_sched_barrier(0);
  }

  wait_lds_and_barrier();   // all waves done reading h (lgkm only; DMA flies)

  float4 bias4[4];
#pragma unroll
  for (int n = 0; n < 4; ++n)
    bias4[n] = *(const float4*)(bias + wv * 64 + n * 16 + g * 4);
#pragma unroll
  for (int m = 0; m < 4; ++m) {
    const int row = m * 16 + l15;
    const int sw  = (row & 7) << 4;
#pragma unroll
    for (int n = 0; n < 4; ++n) {
      const float v0 = fmaxf(acc[m][n][0] + bias4[n].x, 0.f);
      const float v1 = fmaxf(acc[m][n][1] + bias4[n].y, 0.f);
      const float v2 = fmaxf(acc[m][n][2] + bias4[n].z, 0.f);
      const float v3 = fmaxf(acc[m][n][3] + bias4[n].w, 0.f);
      uint2 o;
      o.x = f2bf(v0) | ((unsigned)f2bf(v1) << 16);
      o.y = f2bf(v2) | ((unsigned)f2bf(v3) << 16);
      const int c0 = (wv * 64 + n * 16 + g * 4) * 2;
      *(uint2*)((char*)h + row * 1024 + (c0 ^ sw)) = o;
    }
  }
  wait_lds_and_barrier();   // h writes visible
}

// ---------------- fused mega-kernel --------------------------------------
__global__ __launch_bounds__(512, 2) void fused_nbeats(
    const float* __restrict__ x,
    const unsigned short* __restrict__ W1p, const float* __restrict__ b1,
    const float* __restrict__ b2, const float* __restrict__ b3,
    const float* __restrict__ b4,
    const bf16x8* __restrict__ Wtp,
    const bf16x8* __restrict__ basp,
    float* __restrict__ out) {
  __shared__ __align__(16) unsigned short h[ROWS * 512];    // 64 KB
  __shared__ __align__(16) unsigned short Wc[2][16384];     // 2 x 32 KB

  const int tid  = threadIdx.x;
  const int lane = tid & 63;
  const int wv   = tid >> 6;
  const int l15  = lane & 15, g = lane >> 4;
  const int r0   = blockIdx.x * ROWS;
  const char* Wall = (const char*)W1p;      // W1..W4 consecutive, 32KB chunks

  int rb[4], am[4];
#pragma unroll
  for (int m = 0; m < 4; ++m) {
    const int row = m * 16 + l15;
    rb[m] = row * 1024;
    am[m] = (row & 7) << 4;
  }

  // ---- issue DMA for chunks 0,1 (fly during x-phase) ----
  const int woff = wv * 4096 + lane * 16;
#pragma unroll
  for (int G = 0; G < 2; ++G) {
    const char* gsrc = Wall + (size_t)G * 32768 + woff;
    char* ldst = (char*)Wc[G & 1] + woff;
#pragma unroll
    for (int j = 0; j < 4; ++j)
      async_copy16(gsrc + j * 1024, ldst + j * 1024);
  }

  // ---- phase 0: x fp32 -> h bf16 (swizzled rows, 1024B stride) ----
  {
    const float4* xs = (const float4*)(x + (size_t)r0 * 512);
#pragma unroll
    for (int j = 0; j < 16; ++j) {
      const int f = tid + j * 512;          // float4 index in [64][128]
      const int row = f >> 7, c4 = f & 127;
      const float4 v = xs[f];
      uint2 o;
      o.x = f2bf(v.x) | ((unsigned)f2bf(v.y) << 16);
      o.y = f2bf(v.z) | ((unsigned)f2bf(v.w) << 16);
      *(uint2*)((char*)h + row * 1024 + ((c4 * 8) ^ ((row & 7) << 4))) = o;
    }
  }
  wait_lds_and_barrier();

  // ---- 4 FC+ReLU layers (in place on h) ----
  layer512<0>(h, Wc, Wall, b1, wv, lane, rb, am);
  layer512<1>(h, Wc, Wall, b2, wv, lane, rb, am);
  layer512<2>(h, Wc, Wall, b3, wv, lane, rb, am);
  layer512<3>(h, Wc, Wall, b4, wv, lane, rb, am);

  // ---- theta = h4 @ Wt^T : wave wv -> theta cols wv*16..+15 ----
  // theta written into Wc[0] (free now), [64 rows][128] bf16, 256B rows.
  unsigned short* thetaL = Wc[0];
  {
    const bf16x8* tb = Wtp + (size_t)wv * 1024 + lane;
    bf16x8 tv[4];                          // depth-4 / dist-3 rolling
#pragma unroll
    for (int s = 0; s < 3; ++s) tv[s] = tb[s * 64];

    f32x4 tacc[4];
#pragma unroll
    for (int m = 0; m < 4; ++m) tacc[m] = (f32x4){0.f, 0.f, 0.f, 0.f};
#pragma unroll
    for (int ks = 0; ks < 16; ++ks) {
      if (ks < 13) tv[(ks + 3) & 3] = tb[(ks + 3) * 64];
      bf16x8 av[4];
      const int kb = ks * 64 + g * 16;
#pragma unroll
      for (int m = 0; m < 4; ++m)
        av[m] = *(const bf16x8*)((const char*)h + rb[m] + (kb ^ am[m]));
#pragma unroll
      for (int m = 0; m < 4; ++m)
        tacc[m] = __builtin_amdgcn_mfma_f32_16x16x32_bf16(
            tv[ks & 3], av[m], tacc[m], 0, 0, 0);
    }
    wait_lds_and_barrier();   // h reads done before Wc[0] overwrite? (Wc != h, but sync wave drift)
#pragma unroll
    for (int m = 0; m < 4; ++m) {
      const int row = m * 16 + l15;
      const int sw  = (row & 7) << 4;
      uint2 o;
      o.x = f2bf(tacc[m][0]) | ((unsigned)f2bf(tacc[m][1]) << 16);
      o.y = f2bf(tacc[m][2]) | ((unsigned)f2bf(tacc[m][3]) << 16);
      const int c0 = (wv * 16 + g * 4) * 2;
      *(uint2*)((char*)thetaL + row * 256 + (c0 ^ sw)) = o;
    }
  }
  wait_lds_and_barrier();

  // ---- backcast/forecast: out = theta @ basT^T (wave wv -> 80 cols) ----
  {
    const bf16x8* bb = basp + (size_t)wv * 1280 + lane;   // cf = wv*5+n, KS=4
    bf16x8 bvv[2][5];                      // rolling depth-2
#pragma unroll
    for (int n = 0; n < 5; ++n) bvv[0][n] = bb[n * 256];

    f32x4 facc[4][5];
#pragma unroll
    for (int m = 0; m < 4; ++m)
#pragma unroll
      for (int n = 0; n < 5; ++n) facc[m][n] = (f32x4){0.f, 0.f, 0.f, 0.f};
    int rb2[4];
#pragma unroll
    for (int m = 0; m < 4; ++m) rb2[m] = (m * 16 + l15) * 256;
#pragma unroll
    for (int ks = 0; ks < 4; ++ks) {
      if (ks < 3) {
#pragma unroll
        for (int n = 0; n < 5; ++n) bvv[(ks + 1) & 1][n] = bb[n * 256 + (ks + 1) * 64];
      }
      bf16x8 av[4];
      const int kb = ks * 64 + g * 16;
#pragma unroll
      for (int m = 0; m < 4; ++m)
        av[m] = *(const bf16x8*)((const char*)thetaL + rb2[m] + (kb ^ am[m]));
#pragma unroll
      for (int n = 0; n < 5; ++n)
#pragma unroll
        for (int m = 0; m < 4; ++m)
          facc[m][n] = __builtin_amdgcn_mfma_f32_16x16x32_bf16(
              bvv[ks & 1][n], av[m], facc[m][n], 0, 0, 0);
    }
    // store: lane (g,l15), frag (m,n): row r0+m*16+l15,
    // cols wv*80+n*16+g*4+(0..3) -> one dwordx4
#pragma unroll
    for (int n = 0; n < 5; ++n) {
      const int c0 = wv * 80 + n * 16 + g * 4;
#pragma unroll
      for (int m = 0; m < 4; ++m) {
        const int row = r0 + m * 16 + l15;
        float4 o = make_float4(facc[m][n][0], facc[m][n][1],
                               facc[m][n][2], facc[m][n][3]);
        if (c0 < 512)
          *(float4*)(out + (size_t)row * 512 + c0) = o;
        else
          *(float4*)(out + (size_t)BATCH * 512 + (size_t)row * 128 + (c0 - 512)) = o;
      }
    }
  }
}

// ---------------- launch --------------------------------------------------
extern "C" void kernel_launch(void* const* d_in, const int* in_sizes, int n_in,
                              void* d_out, int out_size, void* d_ws, size_t ws_size,
                              hipStream_t stream) {
  const float* x  = (const float*)d_in[0];
  const float* W1 = (const float*)d_in[1];
  const float* b1 = (const float*)d_in[2];
  const float* W2 = (const float*)d_in[3];
  const float* b2 = (const float*)d_in[4];
  const float* W3 = (const float*)d_in[5];
  const float* b3 = (const float*)d_in[6];
  const float* W4 = (const float*)d_in[7];
  const float* b4 = (const float*)d_in[8];
  const float* Wt = (const float*)d_in[9];

  unsigned short* ws  = (unsigned short*)d_ws;
  unsigned short* W1p = ws;                       // 262144 elems each, CONSECUTIVE
  unsigned short* W2p = ws + 262144;
  unsigned short* W3p = ws + 524288;
  unsigned short* W4p = ws + 786432;
  unsigned short* Wtp = ws + 1048576;             // 65536
  unsigned short* basp = ws + 1114112;            // 640*128 = 81920

  prep_kernel<<<584, 256, 0, stream>>>(W1, W2, W3, W4, Wt,
                                       W1p, W2p, W3p, W4p, Wtp, basp);
  fused_nbeats<<<BATCH / ROWS, 512, 0, stream>>>(
      x, W1p, b1, b2, b3, b4,
      (const bf16x8*)Wtp, (const bf16x8*)basp, (float*)d_out);
}